// Round 4
// baseline (11018.790 us; speedup 1.0000x reference)
//
#include <hip/hip_runtime.h>

#define BB 2
#define SS 2048
#define NH 32
#define NKV 8
#define GQ (NH / NKV)
#define DD 128

// One block per output row (b, s, h). 256 threads. Pure fp32, no LDS tiling
// tricks, no bf16 — correctness bisect: tests ONLY the problem assumptions
// (input order q,k,v; [B,S,H,D]/[B,S,Hkv,D] row-major layouts; kh = h/GQ;
// causal t <= s; scale = 1/sqrt(D)).
__global__ __launch_bounds__(256)
void attn_naive(const float* __restrict__ qp, const float* __restrict__ kp,
                const float* __restrict__ vp, float* __restrict__ op)
{
  __shared__ float qrow[DD];
  __shared__ float sc[SS];
  __shared__ float red[16];

  const int tid = threadIdx.x;
  const int bid = blockIdx.x;
  const int b   = bid / (SS * NH);
  const int rem = bid % (SS * NH);
  const int s   = rem / NH;
  const int h   = rem % NH;
  const int kh  = h / GQ;
  const float scale = 0.08838834764831845f;   // 1/sqrt(128)

  const int wave = tid >> 6;
  const int lane = tid & 63;

  // stage q row
  const float* qr = qp + (((size_t)b * SS + s) * NH + h) * DD;
  if (tid < DD) qrow[tid] = qr[tid];
  __syncthreads();

  // phase 1: scores sc[t] = scale * dot(q_row, k_t), t = 0..s
  for (int t = wave; t <= s; t += 4) {
    const float* kr = kp + (((size_t)b * SS + t) * NKV + kh) * DD;
    float part = qrow[lane] * kr[lane] + qrow[lane + 64] * kr[lane + 64];
    #pragma unroll
    for (int off = 32; off; off >>= 1) part += __shfl_xor(part, off);
    if (lane == 0) sc[t] = part * scale;
  }
  __syncthreads();

  // phase 2: row max
  float m = -1e30f;
  for (int t = tid; t <= s; t += 256) m = fmaxf(m, sc[t]);
  #pragma unroll
  for (int off = 32; off; off >>= 1) m = fmaxf(m, __shfl_xor(m, off));
  if (lane == 0) red[wave] = m;
  __syncthreads();
  m = fmaxf(fmaxf(red[0], red[1]), fmaxf(red[2], red[3]));

  // phase 3: exponentiate in place + row sum
  float lsum = 0.f;
  for (int t = tid; t <= s; t += 256) {
    const float p = __expf(sc[t] - m);
    sc[t] = p;
    lsum += p;
  }
  #pragma unroll
  for (int off = 32; off; off >>= 1) lsum += __shfl_xor(lsum, off);
  if (lane == 0) red[8 + wave] = lsum;
  __syncthreads();
  lsum = red[8] + red[9] + red[10] + red[11];

  // phase 4: O[d] = (1/lsum) * sum_t sc[t] * v[t][d]   (coalesced over d)
  const float inv = 1.f / lsum;
  for (int d = tid; d < DD; d += 256) {
    float acc = 0.f;
    for (int t = 0; t <= s; ++t)
      acc += sc[t] * vp[(((size_t)b * SS + t) * NKV + kh) * DD + d];
    op[(((size_t)b * SS + s) * NH + h) * DD + d] = acc * inv;
  }
}

extern "C" void kernel_launch(void* const* d_in, const int* in_sizes, int n_in,
                              void* d_out, int out_size, void* d_ws, size_t ws_size,
                              hipStream_t stream) {
  const float* q = (const float*)d_in[0];
  const float* k = (const float*)d_in[1];
  const float* v = (const float*)d_in[2];
  float* out = (float*)d_out;
  dim3 grid(BB * SS * NH);   // one block per output row
  dim3 block(256);
  attn_naive<<<grid, block, 0, stream>>>(q, k, v, out);
}